// Round 9
// baseline (293.917 us; speedup 1.0000x reference)
//
#include <hip/hip_runtime.h>

typedef __attribute__((ext_vector_type(8))) short bf16x8;
typedef __attribute__((ext_vector_type(4))) short s16x4;
typedef __attribute__((ext_vector_type(4))) float f32x4;
typedef __attribute__((ext_vector_type(16))) float f32x16;
typedef __attribute__((ext_vector_type(4))) unsigned int uint4v;

__device__ __forceinline__ unsigned short f2bf(float f) {
    unsigned u = __builtin_bit_cast(unsigned, f);
    return (unsigned short)((u + 0x7FFFu + ((u >> 16) & 1u)) >> 16);
}

// ---------------------------------------------------------------------------
// prep: conv2_w [64][32][5][5] fp32 -> wt bf16 [25 taps][64 co][32 ci]
// ---------------------------------------------------------------------------
__global__ __launch_bounds__(256) void k_prep_w2(
    const float* __restrict__ w, unsigned short* __restrict__ wt)
{
    int i = blockIdx.x * 256 + threadIdx.x;
    if (i >= 51200) return;
    int ci = i & 31, co = (i >> 5) & 63, tp = i >> 11;
    wt[i] = f2bf(w[(co * 32 + ci) * 25 + tp]);
}

// ---------------------------------------------------------------------------
// prep: fc1_w [1024][3136 = co*49+s] fp32 -> bf16 [1024][3136 = s*64+co]
// ---------------------------------------------------------------------------
__global__ __launch_bounds__(256) void k_prep_fw1(
    const float* __restrict__ w, unsigned short* __restrict__ o)
{
    int n = blockIdx.x;
    const float* src = w + (size_t)n * 3136;
    unsigned short* dst = o + (size_t)n * 3136;
    for (int j = threadIdx.x; j < 3136; j += 256) {
        int co = j & 63, s = j >> 6;
        dst[j] = f2bf(src[co * 49 + s]);
    }
}

// ---------------------------------------------------------------------------
// Kernel A: conv1 + top-4 mask + threshold ReLU + 2x2 pool.
// Thread = (pooled position, channel-HALF). Top-4 over 32 ch = two local
// top-4-of-16 + cross-lane bitonic merge with partner lane (shfl_xor 1).
// Output: zero-halo padded NHWC bf16 [B][18][18][32]
// ---------------------------------------------------------------------------
__global__ __launch_bounds__(512) void k_conv1_topk_pool(
    const float* __restrict__ x,
    const float* __restrict__ w1,
    const float* __restrict__ t,
    unsigned short* __restrict__ out)
{
    __shared__ float xs[32 * 32];
    __shared__ float ws[25 * 32];    // [tap][c]
    const int b = blockIdx.x;
    const int tid = threadIdx.x;
    unsigned short* ob = out + b * 10368;

    // zero the halo (disjoint from interior writes, no barrier needed)
    for (int p = tid; p < 324; p += 512) {
        int y = p / 18, xx = p % 18;
        if (y < 2 || y >= 16 || xx < 2 || xx >= 16) {
            uint4v z = {0u, 0u, 0u, 0u};
            uint4v* dst = (uint4v*)(ob + p * 32);
            dst[0] = z; dst[1] = z; dst[2] = z; dst[3] = z;
        }
    }

    for (int i = tid; i < 1024; i += 512) xs[i] = 0.f;
    // stage w1 transposed: ws[tap*32+c] = w1[c*25+tap]
    for (int j = tid; j < 800; j += 512)
        ws[j] = w1[(j & 31) * 25 + (j >> 5)];
    __syncthreads();
    const float* xb = x + b * 784;
    for (int i = tid; i < 784; i += 512) {
        int y = i / 28, xx = i % 28;
        xs[(y + 2) * 32 + (xx + 2)] = xb[i];
    }
    __syncthreads();

    if (tid >= 392) return;          // all barriers are above this point
    const int h   = tid & 1;         // channel half (0: ch0-15, 1: ch16-31)
    const int pos = tid >> 1;
    const int ph = pos / 14, pw = pos % 14;

    float pmax[16];
#pragma unroll
    for (int c = 0; c < 16; c++) pmax[c] = -3.0e38f;

#pragma unroll 1
    for (int dy = 0; dy < 2; dy++) {
        float v0[16], v1[16];
#pragma unroll
        for (int c = 0; c < 16; c++) { v0[c] = 0.f; v1[c] = 0.f; }
        const int row0 = 2 * ph + dy;
        const int col0 = 2 * pw;

#pragma unroll 1
        for (int ky = 0; ky < 5; ky++) {
            const float* r = xs + (row0 + ky) * 32 + col0;
            float tr[6];
#pragma unroll
            for (int j = 0; j < 6; j++) tr[j] = r[j];
            const float* wk = ws + (ky * 5) * 32 + h * 16;
#pragma unroll
            for (int kx = 0; kx < 5; kx++) {
                const float p0 = tr[kx];
                const float p1 = tr[kx + 1];
                const float* wrow = wk + kx * 32;
#pragma unroll
                for (int cg = 0; cg < 4; cg++) {
                    const f32x4 w4 = *(const f32x4*)(wrow + cg * 4);
#pragma unroll
                    for (int j = 0; j < 4; j++) {
                        v0[cg * 4 + j] = fmaf(p0, w4[j], v0[cg * 4 + j]);
                        v1[cg * 4 + j] = fmaf(p1, w4[j], v1[cg * 4 + j]);
                    }
                }
            }
        }
        // ---- local top-4-of-16 (min/max insertion), window 0 and 1 ----
        float a0 = -3.0e38f, b0 = -3.0e38f, c0 = -3.0e38f, d0 = -3.0e38f;
        float a1 = -3.0e38f, b1 = -3.0e38f, c1 = -3.0e38f, d1 = -3.0e38f;
#pragma unroll
        for (int c = 0; c < 16; c++) {
            const float x0 = v0[c];
            const float m01 = fminf(a0, x0);  a0 = fmaxf(a0, x0);
            const float m02 = fminf(b0, m01); b0 = fmaxf(b0, m01);
            const float m03 = fminf(c0, m02); c0 = fmaxf(c0, m02);
            d0 = fmaxf(d0, m03);
            const float x1 = v1[c];
            const float m11 = fminf(a1, x1);  a1 = fmaxf(a1, x1);
            const float m12 = fminf(b1, m11); b1 = fmaxf(b1, m11);
            const float m13 = fminf(c1, m12); c1 = fmaxf(c1, m12);
            d1 = fmaxf(d1, m13);
        }
        // ---- cross-lane merge with partner half (bitonic split):
        //      4th of union = min(max(a,d'),max(b,c'),max(c,b'),max(d,a'))
        const float pa0 = __shfl_xor(a0, 1), pb0 = __shfl_xor(b0, 1);
        const float pc0 = __shfl_xor(c0, 1), pd0 = __shfl_xor(d0, 1);
        const float t2_0 = fminf(fminf(fmaxf(a0, pd0), fmaxf(b0, pc0)),
                                 fminf(fmaxf(c0, pb0), fmaxf(d0, pa0)));
        const float pa1 = __shfl_xor(a1, 1), pb1 = __shfl_xor(b1, 1);
        const float pc1 = __shfl_xor(c1, 1), pd1 = __shfl_xor(d1, 1);
        const float t2_1 = fminf(fminf(fmaxf(a1, pd1), fmaxf(b1, pc1)),
                                 fminf(fmaxf(c1, pb1), fmaxf(d1, pa1)));
        // ---- mask (keep >= 4th largest of 32) + running pool max ----
#pragma unroll
        for (int c = 0; c < 16; c++) {
            const float m0 = (v0[c] >= t2_0) ? v0[c] : 0.f;
            const float m1 = (v1[c] >= t2_1) ? v1[c] : 0.f;
            pmax[c] = fmaxf(pmax[c], fmaxf(m0, m1));
        }
    }

    unsigned short* op = ob + ((ph + 2) * 18 + (pw + 2)) * 32 + h * 16;
    const float* tp = t + h * 16;
    unsigned pk[8];
#pragma unroll
    for (int i = 0; i < 8; i++) {
        const float v0 = fmaxf(pmax[2 * i] - tp[2 * i], 0.f);
        const float v1 = fmaxf(pmax[2 * i + 1] - tp[2 * i + 1], 0.f);
        pk[i] = (unsigned)f2bf(v0) | ((unsigned)f2bf(v1) << 16);
    }
    ((uint4v*)op)[0] = *(uint4v*)&pk[0];
    ((uint4v*)op)[1] = *(uint4v*)&pk[4];
}

// ---------------------------------------------------------------------------
// Kernel B: conv2 implicit-GEMM, mfma_f32_32x32x16_bf16.
// Block = 1 image, 4 waves; wave = quad owns tiles {quad, quad+4} run
// SEQUENTIALLY with acc[1][2] (32 AGPR) -> ~100 regs, launch_bounds(256,4)
// caps at 128 => 4 waves/SIMD. A-reads are ds_read_b64 from a [324][36]
// short image (72B rows: 18p mod 32 distinct over 16 lanes => conflict-free;
// b128's 16B units can only hit 8 bank-groups => inherent 2-way, avoided).
// Per-tile epilogue: relu(+bias), x-pool in-lane, bf16 -> separate pool LDS
// (bf16 max == round(fp32 max): monotone rounding, non-negative).
// Final: y-pool via u16 compare. flat [B][49*64] bf16.
// ---------------------------------------------------------------------------
__global__ __launch_bounds__(256, 4) void k_conv2_mfma(
    const unsigned short* __restrict__ in,    // [B][324][32] bf16 padded NHWC
    const unsigned short* __restrict__ wt,    // [25][64][32] bf16
    const float* __restrict__ bias,
    unsigned short* __restrict__ flat)        // [B][3136] bf16
{
    __shared__ __align__(16) unsigned short img[324 * 36];   // 23328 B
    __shared__ __align__(16) unsigned short pool[98 * 64];   // 12544 B
    const int b    = blockIdx.x;
    const int tid  = threadIdx.x;
    const int quad = tid >> 6, lane = tid & 63;
    const int col  = lane & 31;               // A row / B col
    const int hi   = lane >> 5;               // k-half

    // ---- stage image into [324][36] shorts via b64 units ----
    const unsigned short* src = in + (size_t)b * 10368;
    for (int i = tid; i < 2592; i += 256) {
        const int p = i >> 3, u = i & 7;
        *(s16x4*)(img + p * 36 + u * 4) = *(const s16x4*)(src + p * 32 + u * 4);
    }
    __syncthreads();

    const unsigned short* wlane = wt + col * 32 + hi * 8;
    const float bv0 = bias[col];
    const float bv1 = bias[32 + col];

#pragma unroll
    for (int ts = 0; ts < 2; ts++) {
        const int tl = quad + 4 * ts;
        if (tl < 7) {
            int m = tl * 32 + col;
            m = m > 195 ? 195 : m;
            const int y0 = m / 14, x0 = m - y0 * 14;
            const int abase = (y0 * 18 + x0) * 36 + hi * 8;

            f32x16 acc0, acc1;
#pragma unroll
            for (int e = 0; e < 16; e++) { acc0[e] = 0.f; acc1[e] = 0.f; }

#pragma unroll
            for (int ky = 0; ky < 5; ky++) {
#pragma unroll
                for (int kx = 0; kx < 5; kx++) {
                    const unsigned short* wp = wlane + (ky * 5 + kx) * 2048;
                    const bf16x8 b00 = *(const bf16x8*)(wp);           // ks0 g0
                    const bf16x8 b01 = *(const bf16x8*)(wp + 1024);    // ks0 g1
                    const bf16x8 b10 = *(const bf16x8*)(wp + 16);      // ks1 g0
                    const bf16x8 b11 = *(const bf16x8*)(wp + 1040);    // ks1 g1
                    const int ao = abase + (ky * 18 + kx) * 36;
                    bf16x8 a0, a1;
                    *(s16x4*)&a0       = *(const s16x4*)(img + ao);
                    *((s16x4*)&a0 + 1) = *(const s16x4*)(img + ao + 4);
                    *(s16x4*)&a1       = *(const s16x4*)(img + ao + 16);
                    *((s16x4*)&a1 + 1) = *(const s16x4*)(img + ao + 20);
                    acc0 = __builtin_amdgcn_mfma_f32_32x32x16_bf16(
                        a0, b00, acc0, 0, 0, 0);
                    acc1 = __builtin_amdgcn_mfma_f32_32x32x16_bf16(
                        a0, b01, acc1, 0, 0, 0);
                    acc0 = __builtin_amdgcn_mfma_f32_32x32x16_bf16(
                        a1, b10, acc0, 0, 0, 0);
                    acc1 = __builtin_amdgcn_mfma_f32_32x32x16_bf16(
                        a1, b11, acc1, 0, 0, 0);
                }
            }
            // ---- per-tile epilogue: relu(+b), x-pool in-lane, bf16 pool ----
            // C row = (e&3) + 8*(e>>2) + 4*hi; pairs (2q,2q+1) in-lane.
#pragma unroll
            for (int R = 0; R < 4; R++) {
#pragma unroll
                for (int q = 0; q < 2; q++) {
                    const int m2 = tl * 32 + 8 * R + 4 * hi + 2 * q;
                    if (m2 < 196) {
                        const int e = 4 * R + 2 * q;
                        const int y = m2 / 14, x = m2 - y * 14;   // x even
                        const int po = (y * 7 + (x >> 1)) * 64 + col;
                        pool[po] = f2bf(
                            fmaxf(fmaxf(acc0[e], acc0[e + 1]) + bv0, 0.f));
                        pool[po + 32] = f2bf(
                            fmaxf(fmaxf(acc1[e], acc1[e + 1]) + bv1, 0.f));
                    }
                }
            }
        }
    }
    __syncthreads();
    // ---- y-pool (rows 2py, 2py+1): u16 compare == bf16 compare (>=0) ----
    unsigned short* fb = flat + (size_t)b * 3136;
    for (int j = tid; j < 3136; j += 256) {
        const int co = j & 63, s = j >> 6;
        const int py = s / 7, px = s - py * 7;
        const unsigned short v0 = pool[((2 * py) * 7 + px) * 64 + co];
        const unsigned short v1 = pool[((2 * py + 1) * 7 + px) * 64 + co];
        fb[j] = v0 > v1 ? v0 : v1;
    }
}

// ---------------------------------------------------------------------------
// Kernel C: fc1 MFMA GEMM. out[2048,1024] = relu(A[2048,3136] @ B^T + b), bf16.
// Tile 128x64, 4 waves (2x2 of 64x32), BK=32.
// ---------------------------------------------------------------------------
__global__ __launch_bounds__(256) void k_fc1_mfma(
    const unsigned short* __restrict__ A,     // [2048][3136] bf16
    const unsigned short* __restrict__ Bw,    // [1024][3136] bf16 (permuted)
    const float* __restrict__ bias,
    unsigned short* __restrict__ out)         // [2048][1024] bf16
{
    __shared__ unsigned short As[128 * 40];   // +8 pad
    __shared__ unsigned short Bs[64 * 40];
    const int tid = threadIdx.x;
    const int m0 = blockIdx.y * 128;
    const int n0 = blockIdx.x * 64;
    const int wave = tid >> 6, lane = tid & 63;
    const int laneM = lane & 15, chunk = lane >> 4;
    const int wr = (wave >> 1) * 64;
    const int wc = (wave & 1) * 32;

    const int arow = tid >> 1;                // 0..127
    const int aco  = (tid & 1) * 16;          // short offset (2 chunks)
    const int brow = tid >> 2;                // 0..63
    const int bco  = (tid & 3) * 8;

    f32x4 acc[4][2];
#pragma unroll
    for (int i = 0; i < 4; i++)
#pragma unroll
        for (int j = 0; j < 2; j++) acc[i][j] = (f32x4){0.f, 0.f, 0.f, 0.f};

    const unsigned short* aptr = A  + (size_t)(m0 + arow) * 3136 + aco;
    const unsigned short* bptr = Bw + (size_t)(n0 + brow) * 3136 + bco;

    for (int k0 = 0; k0 < 3136; k0 += 32) {
        const bf16x8 a0 = *(const bf16x8*)(aptr);
        const bf16x8 a1 = *(const bf16x8*)(aptr + 8);
        const bf16x8 bb = *(const bf16x8*)(bptr);
        aptr += 32; bptr += 32;
        __syncthreads();
        *(bf16x8*)&As[arow * 40 + aco] = a0;
        *(bf16x8*)&As[arow * 40 + aco + 8] = a1;
        *(bf16x8*)&Bs[brow * 40 + bco] = bb;
        __syncthreads();

        bf16x8 af[4], bf[2];
#pragma unroll
        for (int rt = 0; rt < 4; rt++)
            af[rt] = *(const bf16x8*)&As[(wr + rt * 16 + laneM) * 40 + chunk * 8];
#pragma unroll
        for (int ct = 0; ct < 2; ct++)
            bf[ct] = *(const bf16x8*)&Bs[(wc + ct * 16 + laneM) * 40 + chunk * 8];
#pragma unroll
        for (int rt = 0; rt < 4; rt++)
#pragma unroll
            for (int ct = 0; ct < 2; ct++)
                acc[rt][ct] = __builtin_amdgcn_mfma_f32_16x16x32_bf16(
                    af[rt], bf[ct], acc[rt][ct], 0, 0, 0);
    }

#pragma unroll
    for (int ct = 0; ct < 2; ct++) {
        const int col = n0 + wc + ct * 16 + laneM;
        const float bvv = bias[col];
#pragma unroll
        for (int rt = 0; rt < 4; rt++) {
#pragma unroll
            for (int r = 0; r < 4; r++) {
                const int row = m0 + wr + rt * 16 + chunk * 4 + r;
                out[(size_t)row * 1024 + col] =
                    f2bf(fmaxf(acc[rt][ct][r] + bvv, 0.f));
            }
        }
    }
}

// ---------------------------------------------------------------------------
// Kernel D: fc2. act bf16 [2048][1024] @ w[10][1024]^T + b -> fp32 [2048][10]
// ---------------------------------------------------------------------------
__global__ __launch_bounds__(256) void k_fc2(
    const unsigned short* __restrict__ act,
    const float* __restrict__ w,
    const float* __restrict__ bias,
    float* __restrict__ out)
{
    const int row  = blockIdx.x * 4 + (threadIdx.x >> 6);
    const int lane = threadIdx.x & 63;
    const unsigned short* a = act + (size_t)row * 1024;
    float acc[10] = {};
    for (int k = lane; k < 1024; k += 64) {
        const float av = __builtin_bit_cast(float, (unsigned)a[k] << 16);
#pragma unroll
        for (int j = 0; j < 10; j++)
            acc[j] = fmaf(av, w[j * 1024 + k], acc[j]);
    }
#pragma unroll
    for (int j = 0; j < 10; j++) {
        float s = acc[j];
#pragma unroll
        for (int off = 32; off; off >>= 1) s += __shfl_xor(s, off);
        if (lane == 0) out[(size_t)row * 10 + j] = s + bias[j];
    }
}

// ---------------------------------------------------------------------------
extern "C" void kernel_launch(void* const* d_in, const int* in_sizes, int n_in,
                              void* d_out, int out_size, void* d_ws, size_t ws_size,
                              hipStream_t stream)
{
    const float* x   = (const float*)d_in[0];
    const float* w1  = (const float*)d_in[1];
    const float* tr  = (const float*)d_in[2];
    const float* w2  = (const float*)d_in[3];
    const float* b2  = (const float*)d_in[4];
    const float* fw1 = (const float*)d_in[5];
    const float* fb1 = (const float*)d_in[6];
    const float* fw2 = (const float*)d_in[7];
    const float* fb2 = (const float*)d_in[8];
    float* out = (float*)d_out;

    char* ws = (char*)d_ws;
    unsigned short* padded1 = (unsigned short*)ws;                    // 42,467,328 B
    unsigned short* flat    = (unsigned short*)(ws + 42467328);       // 12,845,056 B
    unsigned short* fc1out  = (unsigned short*)(ws + 55312384);       //  4,194,304 B
    unsigned short* wt2     = (unsigned short*)(ws + 59506688);       //    102,400 B
    unsigned short* fw1p    = (unsigned short*)(ws + 59609088);       //  6,422,528 B

    k_prep_w2<<<200, 256, 0, stream>>>(w2, wt2);
    k_prep_fw1<<<1024, 256, 0, stream>>>(fw1, fw1p);
    k_conv1_topk_pool<<<2048, 512, 0, stream>>>(x, w1, tr, padded1);
    k_conv2_mfma<<<2048, 256, 0, stream>>>(padded1, wt2, b2, flat);
    k_fc1_mfma<<<dim3(16, 16), 256, 0, stream>>>(flat, fw1p, fb1, fc1out);
    k_fc2<<<512, 256, 0, stream>>>(fc1out, fw2, fb2, out);
}

// Round 10
// 258.487 us; speedup vs baseline: 1.1371x; 1.1371x over previous
//
#include <hip/hip_runtime.h>

typedef __attribute__((ext_vector_type(8))) short bf16x8;
typedef __attribute__((ext_vector_type(4))) float f32x4;
typedef __attribute__((ext_vector_type(16))) float f32x16;
typedef __attribute__((ext_vector_type(4))) unsigned int uint4v;

__device__ __forceinline__ unsigned short f2bf(float f) {
    unsigned u = __builtin_bit_cast(unsigned, f);
    return (unsigned short)((u + 0x7FFFu + ((u >> 16) & 1u)) >> 16);
}

// ---------------------------------------------------------------------------
// prep: conv2_w [64][32][5][5] fp32 -> wt bf16 [25 taps][64 co][32 ci]
// ---------------------------------------------------------------------------
__global__ __launch_bounds__(256) void k_prep_w2(
    const float* __restrict__ w, unsigned short* __restrict__ wt)
{
    int i = blockIdx.x * 256 + threadIdx.x;
    if (i >= 51200) return;
    int ci = i & 31, co = (i >> 5) & 63, tp = i >> 11;
    wt[i] = f2bf(w[(co * 32 + ci) * 25 + tp]);
}

// ---------------------------------------------------------------------------
// prep: fc1_w [1024][3136 = co*49+s] fp32 -> bf16 [1024][3136 = s*64+co]
// ---------------------------------------------------------------------------
__global__ __launch_bounds__(256) void k_prep_fw1(
    const float* __restrict__ w, unsigned short* __restrict__ o)
{
    int n = blockIdx.x;
    const float* src = w + (size_t)n * 3136;
    unsigned short* dst = o + (size_t)n * 3136;
    for (int j = threadIdx.x; j < 3136; j += 256) {
        int co = j & 63, s = j >> 6;
        dst[j] = f2bf(src[co * 49 + s]);
    }
}

// ---------------------------------------------------------------------------
// Kernel A: conv1 + top-4 mask + threshold ReLU + 2x2 pool.
// Thread = (pooled position, channel-HALF). Top-4 over 32 ch = two local
// top-4-of-16 + cross-lane bitonic merge with partner lane (shfl_xor 1).
// Output: zero-halo padded NHWC bf16 [B][18][18][32]
// ---------------------------------------------------------------------------
__global__ __launch_bounds__(512) void k_conv1_topk_pool(
    const float* __restrict__ x,
    const float* __restrict__ w1,
    const float* __restrict__ t,
    unsigned short* __restrict__ out)
{
    __shared__ float xs[32 * 32];
    __shared__ float ws[25 * 32];    // [tap][c]
    const int b = blockIdx.x;
    const int tid = threadIdx.x;
    unsigned short* ob = out + b * 10368;

    // zero the halo (disjoint from interior writes, no barrier needed)
    for (int p = tid; p < 324; p += 512) {
        int y = p / 18, xx = p % 18;
        if (y < 2 || y >= 16 || xx < 2 || xx >= 16) {
            uint4v z = {0u, 0u, 0u, 0u};
            uint4v* dst = (uint4v*)(ob + p * 32);
            dst[0] = z; dst[1] = z; dst[2] = z; dst[3] = z;
        }
    }

    for (int i = tid; i < 1024; i += 512) xs[i] = 0.f;
    // stage w1 transposed: ws[tap*32+c] = w1[c*25+tap]
    for (int j = tid; j < 800; j += 512)
        ws[j] = w1[(j & 31) * 25 + (j >> 5)];
    __syncthreads();
    const float* xb = x + b * 784;
    for (int i = tid; i < 784; i += 512) {
        int y = i / 28, xx = i % 28;
        xs[(y + 2) * 32 + (xx + 2)] = xb[i];
    }
    __syncthreads();

    if (tid >= 392) return;          // all barriers are above this point
    const int h   = tid & 1;         // channel half (0: ch0-15, 1: ch16-31)
    const int pos = tid >> 1;
    const int ph = pos / 14, pw = pos % 14;

    float pmax[16];
#pragma unroll
    for (int c = 0; c < 16; c++) pmax[c] = -3.0e38f;

#pragma unroll 1
    for (int dy = 0; dy < 2; dy++) {
        float v0[16], v1[16];
#pragma unroll
        for (int c = 0; c < 16; c++) { v0[c] = 0.f; v1[c] = 0.f; }
        const int row0 = 2 * ph + dy;
        const int col0 = 2 * pw;

#pragma unroll 1
        for (int ky = 0; ky < 5; ky++) {
            const float* r = xs + (row0 + ky) * 32 + col0;
            float tr[6];
#pragma unroll
            for (int j = 0; j < 6; j++) tr[j] = r[j];
            const float* wk = ws + (ky * 5) * 32 + h * 16;
#pragma unroll
            for (int kx = 0; kx < 5; kx++) {
                const float p0 = tr[kx];
                const float p1 = tr[kx + 1];
                const float* wrow = wk + kx * 32;
#pragma unroll
                for (int cg = 0; cg < 4; cg++) {
                    const f32x4 w4 = *(const f32x4*)(wrow + cg * 4);
#pragma unroll
                    for (int j = 0; j < 4; j++) {
                        v0[cg * 4 + j] = fmaf(p0, w4[j], v0[cg * 4 + j]);
                        v1[cg * 4 + j] = fmaf(p1, w4[j], v1[cg * 4 + j]);
                    }
                }
            }
        }
        // ---- local top-4-of-16 (min/max insertion), window 0 and 1 ----
        float a0 = -3.0e38f, b0 = -3.0e38f, c0 = -3.0e38f, d0 = -3.0e38f;
        float a1 = -3.0e38f, b1 = -3.0e38f, c1 = -3.0e38f, d1 = -3.0e38f;
#pragma unroll
        for (int c = 0; c < 16; c++) {
            const float x0 = v0[c];
            const float m01 = fminf(a0, x0);  a0 = fmaxf(a0, x0);
            const float m02 = fminf(b0, m01); b0 = fmaxf(b0, m01);
            const float m03 = fminf(c0, m02); c0 = fmaxf(c0, m02);
            d0 = fmaxf(d0, m03);
            const float x1 = v1[c];
            const float m11 = fminf(a1, x1);  a1 = fmaxf(a1, x1);
            const float m12 = fminf(b1, m11); b1 = fmaxf(b1, m11);
            const float m13 = fminf(c1, m12); c1 = fmaxf(c1, m12);
            d1 = fmaxf(d1, m13);
        }
        // ---- cross-lane merge with partner half (bitonic split):
        //      4th of union = min(max(a,d'),max(b,c'),max(c,b'),max(d,a'))
        const float pa0 = __shfl_xor(a0, 1), pb0 = __shfl_xor(b0, 1);
        const float pc0 = __shfl_xor(c0, 1), pd0 = __shfl_xor(d0, 1);
        const float t2_0 = fminf(fminf(fmaxf(a0, pd0), fmaxf(b0, pc0)),
                                 fminf(fmaxf(c0, pb0), fmaxf(d0, pa0)));
        const float pa1 = __shfl_xor(a1, 1), pb1 = __shfl_xor(b1, 1);
        const float pc1 = __shfl_xor(c1, 1), pd1 = __shfl_xor(d1, 1);
        const float t2_1 = fminf(fminf(fmaxf(a1, pd1), fmaxf(b1, pc1)),
                                 fminf(fmaxf(c1, pb1), fmaxf(d1, pa1)));
        // ---- mask (keep >= 4th largest of 32) + running pool max ----
#pragma unroll
        for (int c = 0; c < 16; c++) {
            const float m0 = (v0[c] >= t2_0) ? v0[c] : 0.f;
            const float m1 = (v1[c] >= t2_1) ? v1[c] : 0.f;
            pmax[c] = fmaxf(pmax[c], fmaxf(m0, m1));
        }
    }

    unsigned short* op = ob + ((ph + 2) * 18 + (pw + 2)) * 32 + h * 16;
    const float* tp = t + h * 16;
    unsigned pk[8];
#pragma unroll
    for (int i = 0; i < 8; i++) {
        const float v0 = fmaxf(pmax[2 * i] - tp[2 * i], 0.f);
        const float v1 = fmaxf(pmax[2 * i + 1] - tp[2 * i + 1], 0.f);
        pk[i] = (unsigned)f2bf(v0) | ((unsigned)f2bf(v1) << 16);
    }
    ((uint4v*)op)[0] = *(uint4v*)&pk[0];
    ((uint4v*)op)[1] = *(uint4v*)&pk[4];
}

// ---------------------------------------------------------------------------
// Kernel B: conv2 implicit-GEMM, mfma_f32_32x32x16_bf16.  (round-8 version,
// 75 µs measured — r9's b64/sequential-tile variant regressed to 100 µs:
// conflicts unchanged, per-wave ILP halved. Keep 4 interleaved acc chains.)
// Block = 1 image, 4 waves: wave = quad, tiles {quad, quad+4} (tile 7 void),
// BOTH 32-co groups per A-read. acc = 2x2 f32x16 = 64 AGPR.
// A from padded LDS ([324][40] shorts); B regs per tap (global, L2-hot).
// Epilogue: x-pool in-lane, y-pool via LDS overlay. flat [B][49*64] bf16.
// ---------------------------------------------------------------------------
__global__ __launch_bounds__(256) void k_conv2_mfma(
    const unsigned short* __restrict__ in,    // [B][324][32] bf16 padded NHWC
    const unsigned short* __restrict__ wt,    // [25][64][32] bf16
    const float* __restrict__ bias,
    unsigned short* __restrict__ flat)        // [B][3136] bf16
{
    __shared__ __align__(16) unsigned short smem[324 * 40];  // 25920 B
    const int b    = blockIdx.x;
    const int tid  = threadIdx.x;
    const int quad = tid >> 6, lane = tid & 63;
    const int col  = lane & 31;               // A row / B col
    const int hi   = lane >> 5;               // k-half

    // ---- stage image into padded LDS [324][40 shorts] ----
    for (int i = tid; i < 1296; i += 256) {
        const int p = i >> 2, c = i & 3;
        const bf16x8 v = *(const bf16x8*)(
            in + (size_t)b * 10368 + p * 32 + c * 8);
        *(bf16x8*)(smem + p * 40 + c * 8) = v;
    }
    __syncthreads();

    // per-lane A base per tile (short offsets into smem)
    int pbase[2];
#pragma unroll
    for (int ts = 0; ts < 2; ts++) {
        int m = (quad + 4 * ts) * 32 + col;
        m = m > 195 ? 195 : m;
        const int y = m / 14, x = m - y * 14;
        pbase[ts] = (y * 18 + x) * 40 + hi * 8;
    }
    const unsigned short* wlane = wt + col * 32 + hi * 8;

    f32x16 acc[2][2];
#pragma unroll
    for (int ts = 0; ts < 2; ts++)
#pragma unroll
        for (int g = 0; g < 2; g++)
#pragma unroll
            for (int e = 0; e < 16; e++) acc[ts][g][e] = 0.f;

#pragma unroll
    for (int ky = 0; ky < 5; ky++) {
#pragma unroll
        for (int kx = 0; kx < 5; kx++) {
            const unsigned short* wp = wlane + (ky * 5 + kx) * 2048;
            const bf16x8 b00 = *(const bf16x8*)(wp);           // ks0 g0
            const bf16x8 b01 = *(const bf16x8*)(wp + 1024);    // ks0 g1
            const bf16x8 b10 = *(const bf16x8*)(wp + 16);      // ks1 g0
            const bf16x8 b11 = *(const bf16x8*)(wp + 1040);    // ks1 g1
            const int toff = (ky * 18 + kx) * 40;
#pragma unroll
            for (int ts = 0; ts < 2; ts++) {
                if (quad + 4 * ts < 7) {
                    const bf16x8 a0 = *(const bf16x8*)(smem + pbase[ts] + toff);
                    acc[ts][0] = __builtin_amdgcn_mfma_f32_32x32x16_bf16(
                        a0, b00, acc[ts][0], 0, 0, 0);
                    acc[ts][1] = __builtin_amdgcn_mfma_f32_32x32x16_bf16(
                        a0, b01, acc[ts][1], 0, 0, 0);
                    const bf16x8 a1 = *(const bf16x8*)(smem + pbase[ts] + toff + 16);
                    acc[ts][0] = __builtin_amdgcn_mfma_f32_32x32x16_bf16(
                        a1, b10, acc[ts][0], 0, 0, 0);
                    acc[ts][1] = __builtin_amdgcn_mfma_f32_32x32x16_bf16(
                        a1, b11, acc[ts][1], 0, 0, 0);
                }
            }
        }
    }

    // ---- epilogue: relu(acc+bias), x-pool in-lane, y-pool via LDS ----
    __syncthreads();                          // all A-reads done; reuse smem
    float* pool = (float*)smem;               // [98][64] f32 = 25088 B
    const float bv0 = bias[col];
    const float bv1 = bias[32 + col];
#pragma unroll
    for (int ts = 0; ts < 2; ts++) {
        const int tl = quad + 4 * ts;
        if (tl < 7) {
#pragma unroll
            for (int g = 0; g < 2; g++) {
                const float bv = g ? bv1 : bv0;
#pragma unroll
                for (int R = 0; R < 4; R++) {
#pragma unroll
                    for (int q = 0; q < 2; q++) {
                        const int m = tl * 32 + 8 * R + 4 * hi + 2 * q;
                        if (m < 196) {
                            // C row (r&3)+8*(r>>2)+4*hi: pairs in-lane
                            const float v = fmaxf(
                                fmaxf(acc[ts][g][4 * R + 2 * q],
                                      acc[ts][g][4 * R + 2 * q + 1]) + bv, 0.f);
                            const int y = m / 14, x = m - y * 14;   // x even
                            pool[(y * 7 + (x >> 1)) * 64 + g * 32 + col] = v;
                        }
                    }
                }
            }
        }
    }
    __syncthreads();
    // y-pool (rows 2py, 2py+1) + bf16 store, same flat layout as before
    for (int j = tid; j < 3136; j += 256) {
        const int co = j & 63, s = j >> 6;
        const int py = s / 7, px = s - py * 7;
        const float v = fmaxf(pool[((2 * py) * 7 + px) * 64 + co],
                              pool[((2 * py + 1) * 7 + px) * 64 + co]);
        flat[(size_t)b * 3136 + j] = f2bf(v);
    }
}

// ---------------------------------------------------------------------------
// Kernel C: fc1 MFMA GEMM. out[2048,1024] = relu(A[2048,3136] @ B^T + b), bf16.
// Tile 64x64, 4 waves (2x2 of 32x32), BK=32. Grid (16,32) = 512 blocks =
// 2 blocks/CU (old 128x64 grid was 256 = 1 block/CU, 12.5% occupancy cap).
// Same per-output K order as before -> bitwise-identical result.
// ---------------------------------------------------------------------------
__global__ __launch_bounds__(256) void k_fc1_mfma(
    const unsigned short* __restrict__ A,     // [2048][3136] bf16
    const unsigned short* __restrict__ Bw,    // [1024][3136] bf16 (permuted)
    const float* __restrict__ bias,
    unsigned short* __restrict__ out)         // [2048][1024] bf16
{
    __shared__ unsigned short As[64 * 40];    // +8 pad
    __shared__ unsigned short Bs[64 * 40];
    const int tid = threadIdx.x;
    const int m0 = blockIdx.y * 64;
    const int n0 = blockIdx.x * 64;
    const int wave = tid >> 6, lane = tid & 63;
    const int laneM = lane & 15, chunk = lane >> 4;
    const int wr = (wave >> 1) * 32;
    const int wc = (wave & 1) * 32;

    const int lrow = tid >> 2;                // 0..63 (load row, A and B)
    const int lco  = (tid & 3) * 8;           // short offset within BK=32

    f32x4 acc[2][2];
#pragma unroll
    for (int i = 0; i < 2; i++)
#pragma unroll
        for (int j = 0; j < 2; j++) acc[i][j] = (f32x4){0.f, 0.f, 0.f, 0.f};

    const unsigned short* aptr = A  + (size_t)(m0 + lrow) * 3136 + lco;
    const unsigned short* bptr = Bw + (size_t)(n0 + lrow) * 3136 + lco;

    for (int k0 = 0; k0 < 3136; k0 += 32) {
        const bf16x8 aa = *(const bf16x8*)(aptr);
        const bf16x8 bb = *(const bf16x8*)(bptr);
        aptr += 32; bptr += 32;
        __syncthreads();   // previous compute done before overwrite
        *(bf16x8*)&As[lrow * 40 + lco] = aa;
        *(bf16x8*)&Bs[lrow * 40 + lco] = bb;
        __syncthreads();

        bf16x8 af[2], bf[2];
#pragma unroll
        for (int rt = 0; rt < 2; rt++)
            af[rt] = *(const bf16x8*)&As[(wr + rt * 16 + laneM) * 40 + chunk * 8];
#pragma unroll
        for (int ct = 0; ct < 2; ct++)
            bf[ct] = *(const bf16x8*)&Bs[(wc + ct * 16 + laneM) * 40 + chunk * 8];
#pragma unroll
        for (int rt = 0; rt < 2; rt++)
#pragma unroll
            for (int ct = 0; ct < 2; ct++)
                acc[rt][ct] = __builtin_amdgcn_mfma_f32_16x16x32_bf16(
                    af[rt], bf[ct], acc[rt][ct], 0, 0, 0);
    }

#pragma unroll
    for (int ct = 0; ct < 2; ct++) {
        const int col = n0 + wc + ct * 16 + laneM;
        const float bvv = bias[col];
#pragma unroll
        for (int rt = 0; rt < 2; rt++) {
#pragma unroll
            for (int r = 0; r < 4; r++) {
                const int row = m0 + wr + rt * 16 + chunk * 4 + r;
                out[(size_t)row * 1024 + col] =
                    f2bf(fmaxf(acc[rt][ct][r] + bvv, 0.f));
            }
        }
    }
}

// ---------------------------------------------------------------------------
// Kernel D: fc2. act bf16 [2048][1024] @ w[10][1024]^T + b -> fp32 [2048][10]
// ---------------------------------------------------------------------------
__global__ __launch_bounds__(256) void k_fc2(
    const unsigned short* __restrict__ act,
    const float* __restrict__ w,
    const float* __restrict__ bias,
    float* __restrict__ out)
{
    const int row  = blockIdx.x * 4 + (threadIdx.x >> 6);
    const int lane = threadIdx.x & 63;
    const unsigned short* a = act + (size_t)row * 1024;
    float acc[10] = {};
    for (int k = lane; k < 1024; k += 64) {
        const float av = __builtin_bit_cast(float, (unsigned)a[k] << 16);
#pragma unroll
        for (int j = 0; j < 10; j++)
            acc[j] = fmaf(av, w[j * 1024 + k], acc[j]);
    }
#pragma unroll
    for (int j = 0; j < 10; j++) {
        float s = acc[j];
#pragma unroll
        for (int off = 32; off; off >>= 1) s += __shfl_xor(s, off);
        if (lane == 0) out[(size_t)row * 10 + j] = s + bias[j];
    }
}

// ---------------------------------------------------------------------------
extern "C" void kernel_launch(void* const* d_in, const int* in_sizes, int n_in,
                              void* d_out, int out_size, void* d_ws, size_t ws_size,
                              hipStream_t stream)
{
    const float* x   = (const float*)d_in[0];
    const float* w1  = (const float*)d_in[1];
    const float* tr  = (const float*)d_in[2];
    const float* w2  = (const float*)d_in[3];
    const float* b2  = (const float*)d_in[4];
    const float* fw1 = (const float*)d_in[5];
    const float* fb1 = (const float*)d_in[6];
    const float* fw2 = (const float*)d_in[7];
    const float* fb2 = (const float*)d_in[8];
    float* out = (float*)d_out;

    char* ws = (char*)d_ws;
    unsigned short* padded1 = (unsigned short*)ws;                    // 42,467,328 B
    unsigned short* flat    = (unsigned short*)(ws + 42467328);       // 12,845,056 B
    unsigned short* fc1out  = (unsigned short*)(ws + 55312384);       //  4,194,304 B
    unsigned short* wt2     = (unsigned short*)(ws + 59506688);       //    102,400 B
    unsigned short* fw1p    = (unsigned short*)(ws + 59609088);       //  6,422,528 B

    k_prep_w2<<<200, 256, 0, stream>>>(w2, wt2);
    k_prep_fw1<<<1024, 256, 0, stream>>>(fw1, fw1p);
    k_conv1_topk_pool<<<2048, 512, 0, stream>>>(x, w1, tr, padded1);
    k_conv2_mfma<<<2048, 256, 0, stream>>>(padded1, wt2, b2, flat);
    k_fc1_mfma<<<dim3(16, 32), 256, 0, stream>>>(flat, fw1p, fb1, fc1out);
    k_fc2<<<512, 256, 0, stream>>>(fc1out, fw2, fb2, out);
}